// Round 1
// baseline (1498.945 us; speedup 1.0000x reference)
//
#include <hip/hip_runtime.h>
#include <cstdint>
#include <cstddef>

// ---------------- hash table params ----------------
#define TBL_LOG 21
static constexpr unsigned TBL = 1u << TBL_LOG;      // 2M buckets for 1M keys
static constexpr unsigned HASH_MUL = 2654435761u;   // Knuth multiplicative

// Build bucket-chained hash of directed-edge keys: key = src*NN + dst (< 1.6e9, fits u32).
__global__ void build_hash_kernel(const int* __restrict__ esrc,
                                  const int* __restrict__ edst,
                                  int* __restrict__ heads,
                                  int* __restrict__ nxt,
                                  int E, unsigned NN) {
    int e = blockIdx.x * blockDim.x + threadIdx.x;
    if (e >= E) return;
    unsigned key = (unsigned)esrc[e] * NN + (unsigned)edst[e];
    unsigned b = (key * HASH_MUL) >> (32 - TBL_LOG);
    nxt[e] = atomicExch(&heads[b], e);
}

// agg[node][u] += feat[e][u] for e with dst[e]==node. One thread per (e,u).
__global__ void agg_kernel(const float* __restrict__ feat,
                           const int* __restrict__ edst,
                           float* __restrict__ agg,
                           long long total) {
    long long i = (long long)blockIdx.x * blockDim.x + threadIdx.x;
    if (i >= total) return;
    int e = (int)(i >> 6);
    int u = (int)(i & 63);
    atomicAdd(&agg[((long long)edst[e] << 6) + u], feat[i]);
}

// Fused: message = agg[src] - revsum ; out = relu([feat, message] @ W + b)
// One wave per edge (grid-stride). lane = output column. W columns in VGPRs.
__global__ __launch_bounds__(256, 3)
void fused_kernel(const float* __restrict__ feat,
                  const int* __restrict__ esrc,
                  const int* __restrict__ edst,
                  const float* __restrict__ agg,
                  const int* __restrict__ heads,
                  const int* __restrict__ nxt,
                  const float* __restrict__ W,
                  const float* __restrict__ bias,
                  float* __restrict__ out,
                  int E, unsigned NN, int totalWaves) {
    const int lane = threadIdx.x & 63;
    const int wave = (int)((blockIdx.x * blockDim.x + threadIdx.x) >> 6);

    // W is (128,64) row-major; lane holds column `lane`: 128 VGPRs.
    float Wc[128];
#pragma unroll
    for (int k = 0; k < 128; ++k) Wc[k] = W[k * 64 + lane];
    const float bv = bias[lane];

    for (int e = wave; e < E; e += totalWaves) {
        const int s = esrc[e];
        const int d = edst[e];
        const float f = feat[((size_t)e << 6) + lane];
        float msg = agg[((size_t)s << 6) + lane];

        // subtract sum of features of all edges with key == (d,s)
        const unsigned rk = (unsigned)d * NN + (unsigned)s;
        int cur = heads[(rk * HASH_MUL) >> (32 - TBL_LOG)];
        while (cur >= 0) {  // wave-uniform chain walk
            if ((unsigned)esrc[cur] * NN + (unsigned)edst[cur] == rk)
                msg -= feat[((size_t)cur << 6) + lane];
            cur = nxt[cur];
        }

        // dot: out[lane] = relu(b + sum_k f[k]*W[k][lane] + sum_k msg[k]*W[64+k][lane])
        float acc0 = bv, acc1 = 0.f;
#pragma unroll
        for (int k = 0; k < 64; ++k) {
            float hk = __uint_as_float(
                __builtin_amdgcn_readlane(__float_as_uint(f), k));
            acc0 = fmaf(hk, Wc[k], acc0);
        }
#pragma unroll
        for (int k = 0; k < 64; ++k) {
            float mk = __uint_as_float(
                __builtin_amdgcn_readlane(__float_as_uint(msg), k));
            acc1 = fmaf(mk, Wc[64 + k], acc1);
        }
        float r = acc0 + acc1;
        out[((size_t)e << 6) + lane] = r > 0.f ? r : 0.f;
    }
}

extern "C" void kernel_launch(void* const* d_in, const int* in_sizes, int n_in,
                              void* d_out, int out_size, void* d_ws, size_t ws_size,
                              hipStream_t stream) {
    // inputs: 0 edge_feature f32 (E,64), 1 edge_src i32 (E), 2 edge_dst i32 (E),
    //         3 graph_indicator i32 (NN) [unused], 4 num_nodes scalar [unused],
    //         5 W f32 (128,64), 6 b f32 (64)
    const float* feat = (const float*)d_in[0];
    const int*   esrc = (const int*)d_in[1];
    const int*   edst = (const int*)d_in[2];
    const float* W    = (const float*)d_in[5];
    const float* bias = (const float*)d_in[6];
    float* out = (float*)d_out;

    const int E  = in_sizes[1];
    const int NN = in_sizes[3];  // graph_indicator has num_nodes elements

    // workspace layout: agg (NN*64 f32) | heads (TBL i32) | nxt (E i32)
    char* ws = (char*)d_ws;
    size_t aggB   = (size_t)NN * 64 * sizeof(float);
    size_t headsB = (size_t)TBL * sizeof(int);
    float* agg  = (float*)ws;
    int*   heads = (int*)(ws + aggB);
    int*   nxt   = (int*)(ws + aggB + headsB);

    hipMemsetAsync(agg, 0, aggB, stream);
    hipMemsetAsync(heads, 0xFF, headsB, stream);  // all-ones = -1 sentinel

    build_hash_kernel<<<(E + 255) / 256, 256, 0, stream>>>(
        esrc, edst, heads, nxt, E, (unsigned)NN);

    long long total = (long long)E * 64;
    agg_kernel<<<(int)((total + 255) / 256), 256, 0, stream>>>(
        feat, edst, agg, total);

    const int blocks = 768;              // 3 blocks/CU at 256 threads
    const int totalWaves = blocks * 4;
    fused_kernel<<<blocks, 256, 0, stream>>>(
        feat, esrc, edst, agg, heads, nxt, W, bias, out,
        E, (unsigned)NN, totalWaves);
}

// Round 2
// 896.970 us; speedup vs baseline: 1.6711x; 1.6711x over previous
//
#include <hip/hip_runtime.h>
#include <cstdint>
#include <cstddef>

// ---------------- hash table params ----------------
#define TBL_LOG 19
static constexpr unsigned TBL = 1u << TBL_LOG;      // 512K buckets, 1M keys
static constexpr unsigned HASH_MUL = 2654435761u;   // Knuth multiplicative

typedef __attribute__((ext_vector_type(8))) short short8;   // 8 bf16 (4 VGPRs)
typedef __attribute__((ext_vector_type(4))) float floatx4;  // MFMA C/D

union U4S8 { uint4 u; short8 s; };

__device__ inline unsigned bf16rn(float x) {                // RNE f32->bf16
    unsigned u = __float_as_uint(x);
    return (u + 0x7FFFu + ((u >> 16) & 1u)) >> 16;
}
__device__ inline unsigned pk2(float a, float b) {
    return bf16rn(a) | (bf16rn(b) << 16);
}

// ---- pack W (128x64 f32, row-major) into 16 MFMA B-fragments of bf16 ----
// frag (s,t): B[k=32s+8q+j][n=16t+(lane&15)], j=0..7, q=lane>>4.
__global__ void wpack_kernel(const float* __restrict__ W, uint4* __restrict__ wsW) {
    const int lane = threadIdx.x;   // 64 threads
    const int n = lane & 15, q = lane >> 4;
    for (int s = 0; s < 4; ++s)
        for (int t = 0; t < 4; ++t) {
            unsigned dw[4];
#pragma unroll
            for (int jj = 0; jj < 4; ++jj) {
                float a = W[(32 * s + 8 * q + 2 * jj) * 64 + 16 * t + n];
                float b = W[(32 * s + 8 * q + 2 * jj + 1) * 64 + 16 * t + n];
                dw[jj] = pk2(a, b);
            }
            wsW[(s * 4 + t) * 64 + lane] = make_uint4(dw[0], dw[1], dw[2], dw[3]);
        }
}

// ---- hash build: key = src*NN + dst ----
__global__ void build_hash_kernel(const int* __restrict__ esrc,
                                  const int* __restrict__ edst,
                                  int* __restrict__ heads,
                                  int* __restrict__ nxt,
                                  int E, unsigned NN) {
    int e = blockIdx.x * blockDim.x + threadIdx.x;
    if (e >= E) return;
    unsigned key = (unsigned)esrc[e] * NN + (unsigned)edst[e];
    unsigned b = (key * HASH_MUL) >> (32 - TBL_LOG);
    nxt[e] = atomicExch(&heads[b], e);
}

// ---- CSR build: histogram -> scan -> scatter ----
__global__ void hist_kernel(const int* __restrict__ edst, int* __restrict__ cnt, int E) {
    int e = blockIdx.x * blockDim.x + threadIdx.x;
    if (e < E) atomicAdd(&cnt[edst[e]], 1);
}

// one block, 1024 threads; writes exclusive offsets to off[] and resets cnt[] to
// cursor start values (cnt is reused as the scatter cursor).
__global__ void scan_kernel(int* __restrict__ cnt, int* __restrict__ off, int NN, int E) {
    __shared__ int sd[1024];
    const int t = threadIdx.x;
    const int chunk = (NN + 1023) >> 10;
    const int lo = t * chunk, hi = min(lo + chunk, NN);
    int local = 0;
    for (int i = lo; i < hi; ++i) local += cnt[i];
    sd[t] = local;
    __syncthreads();
    for (int s = 1; s < 1024; s <<= 1) {
        int v = (t >= s) ? sd[t - s] : 0;
        __syncthreads();
        sd[t] += v;
        __syncthreads();
    }
    int run = sd[t] - local;  // exclusive base
    for (int i = lo; i < hi; ++i) {
        int c = cnt[i];
        off[i] = run;
        cnt[i] = run;   // cursor
        run += c;
    }
    if (t == 0) off[NN] = E;
}

__global__ void scatter_kernel(const int* __restrict__ edst, int* __restrict__ cursor,
                               int* __restrict__ csr, int E) {
    int e = blockIdx.x * blockDim.x + threadIdx.x;
    if (e >= E) return;
    int slot = atomicAdd(&cursor[edst[e]], 1);
    csr[slot] = e;
}

// ---- agg via CSR: one wave per node, lane = column ----
__global__ __launch_bounds__(256)
void agg_csr_kernel(const float* __restrict__ feat, const int* __restrict__ csr,
                    const int* __restrict__ off, float* __restrict__ agg, int NN) {
    const int wid = (blockIdx.x * blockDim.x + threadIdx.x) >> 6;
    const int lane = threadIdx.x & 63;
    if (wid >= NN) return;
    const int i0 = off[wid], i1 = off[wid + 1];
    float acc = 0.f;
    int i = i0;
    for (; i + 4 <= i1; i += 4) {
        int c0 = csr[i], c1 = csr[i + 1], c2 = csr[i + 2], c3 = csr[i + 3];
        float a0 = feat[((long long)c0 << 6) + lane];
        float a1 = feat[((long long)c1 << 6) + lane];
        float a2 = feat[((long long)c2 << 6) + lane];
        float a3 = feat[((long long)c3 << 6) + lane];
        acc += (a0 + a1) + (a2 + a3);
    }
    for (; i < i1; ++i) acc += feat[((long long)csr[i] << 6) + lane];
    agg[((long long)wid << 6) + lane] = acc;
}

// ---- fused: h = [feat, agg[src]-revsum] (bf16, LDS) ; out = relu(h@W + b) via MFMA ----
__global__ __launch_bounds__(256, 2)
void fused_kernel(const float* __restrict__ feat,
                  const int* __restrict__ esrc,
                  const int* __restrict__ edst,
                  const float* __restrict__ agg,
                  const int* __restrict__ heads,
                  const int* __restrict__ nxt,
                  const uint4* __restrict__ wsW,
                  const float* __restrict__ bias,
                  float* __restrict__ out,
                  int E, unsigned NN) {
    // 64 edge rows x 128 bf16 cols, padded to 68 dwords/row (bank-balanced b128)
    __shared__ unsigned lds_h[64 * 68];
    const int tid = threadIdx.x;
    const int lane = tid & 63;
    const int n = lane & 15;
    const int q = lane >> 4;
    const long long base = (long long)blockIdx.x * 64;

    // W fragments: 16 x uint4 coalesced loads (L2-hot), latency hidden by phase 1
    short8 wf[4][4];
#pragma unroll
    for (int s = 0; s < 4; ++s)
#pragma unroll
        for (int t = 0; t < 4; ++t) {
            U4S8 cvt;
            cvt.u = wsW[(s * 4 + t) * 64 + lane];
            wf[s][t] = cvt.s;
        }
    float bv[4];
#pragma unroll
    for (int t = 0; t < 4; ++t) bv[t] = bias[16 * t + n];

    // ---- phase 1: 4 threads/edge, 16 cols each ----
    const int el = tid >> 2;
    const int p = tid & 3;
    const long long e = base + el;
    float4 f0, f1, f2, f3, m0, m1, m2, m3;
    if (e < (long long)E) {
        const float4* fp = (const float4*)(feat + (e << 6) + 16 * p);
        f0 = fp[0]; f1 = fp[1]; f2 = fp[2]; f3 = fp[3];
        const int s = esrc[e], d = edst[e];
        const float4* ap = (const float4*)(agg + ((long long)s << 6) + 16 * p);
        m0 = ap[0]; m1 = ap[1]; m2 = ap[2]; m3 = ap[3];
        const unsigned rk = (unsigned)d * NN + (unsigned)s;
        int cur = heads[(rk * HASH_MUL) >> (32 - TBL_LOG)];
        while (cur >= 0) {
            if ((unsigned)esrc[cur] * NN + (unsigned)edst[cur] == rk) {
                const float4* rp = (const float4*)(feat + ((long long)cur << 6) + 16 * p);
                float4 r0 = rp[0], r1 = rp[1], r2 = rp[2], r3 = rp[3];
                m0.x -= r0.x; m0.y -= r0.y; m0.z -= r0.z; m0.w -= r0.w;
                m1.x -= r1.x; m1.y -= r1.y; m1.z -= r1.z; m1.w -= r1.w;
                m2.x -= r2.x; m2.y -= r2.y; m2.z -= r2.z; m2.w -= r2.w;
                m3.x -= r3.x; m3.y -= r3.y; m3.z -= r3.z; m3.w -= r3.w;
            }
            cur = nxt[cur];
        }
    } else {
        f0 = f1 = f2 = f3 = make_float4(0.f, 0.f, 0.f, 0.f);
        m0 = m1 = m2 = m3 = make_float4(0.f, 0.f, 0.f, 0.f);
    }
    unsigned* row = &lds_h[el * 68];
    *(uint4*)(row + 8 * p) =
        make_uint4(pk2(f0.x, f0.y), pk2(f0.z, f0.w), pk2(f1.x, f1.y), pk2(f1.z, f1.w));
    *(uint4*)(row + 8 * p + 4) =
        make_uint4(pk2(f2.x, f2.y), pk2(f2.z, f2.w), pk2(f3.x, f3.y), pk2(f3.z, f3.w));
    *(uint4*)(row + 32 + 8 * p) =
        make_uint4(pk2(m0.x, m0.y), pk2(m0.z, m0.w), pk2(m1.x, m1.y), pk2(m1.z, m1.w));
    *(uint4*)(row + 32 + 8 * p + 4) =
        make_uint4(pk2(m2.x, m2.y), pk2(m2.z, m2.w), pk2(m3.x, m3.y), pk2(m3.z, m3.w));
    __syncthreads();

    // ---- phase 2: wave w computes edges [16w, 16w+16) x all 64 cols ----
    const int w = tid >> 6;
    floatx4 acc[4];
#pragma unroll
    for (int t = 0; t < 4; ++t) acc[t] = (floatx4){0.f, 0.f, 0.f, 0.f};
#pragma unroll
    for (int s = 0; s < 4; ++s) {
        U4S8 a;
        a.u = *(const uint4*)&lds_h[(16 * w + n) * 68 + 16 * s + 4 * q];
#pragma unroll
        for (int t = 0; t < 4; ++t)
            acc[t] = __builtin_amdgcn_mfma_f32_16x16x32_bf16(a.s, wf[s][t], acc[t], 0, 0, 0);
    }

    // ---- epilogue: C layout col=lane&15, row=4q+reg ----
    const long long rbase = base + 16 * w + 4 * q;
#pragma unroll
    for (int t = 0; t < 4; ++t)
#pragma unroll
        for (int r = 0; r < 4; ++r) {
            long long rr = rbase + r;
            if (rr < (long long)E) {
                float v = acc[t][r] + bv[t];
                out[(rr << 6) + 16 * t + n] = v > 0.f ? v : 0.f;
            }
        }
}

extern "C" void kernel_launch(void* const* d_in, const int* in_sizes, int n_in,
                              void* d_out, int out_size, void* d_ws, size_t ws_size,
                              hipStream_t stream) {
    const float* feat = (const float*)d_in[0];
    const int*   esrc = (const int*)d_in[1];
    const int*   edst = (const int*)d_in[2];
    const float* W    = (const float*)d_in[5];
    const float* bias = (const float*)d_in[6];
    float* out = (float*)d_out;

    const int E  = in_sizes[1];
    const int NN = in_sizes[3];

    // workspace layout (16B aligned)
    char* ws = (char*)d_ws;
    size_t o = 0;
    auto alloc = [&](size_t bytes) { void* p = ws + o; o = (o + bytes + 15) & ~(size_t)15; return p; };
    float* agg   = (float*)alloc((size_t)NN * 64 * sizeof(float));   // 10.24 MB
    int*   heads = (int*)alloc((size_t)TBL * sizeof(int));           // 2 MB
    int*   nxt   = (int*)alloc((size_t)E * sizeof(int));             // 4 MB
    int*   cnt   = (int*)alloc((size_t)NN * sizeof(int));            // 160 KB (also cursor)
    int*   off   = (int*)alloc((size_t)(NN + 1) * sizeof(int));      // 160 KB
    int*   csr   = (int*)alloc((size_t)E * sizeof(int));             // 4 MB
    uint4* wsW   = (uint4*)alloc((size_t)16 * 64 * sizeof(uint4));   // 16 KB

    hipMemsetAsync(cnt, 0, (size_t)NN * sizeof(int), stream);
    hipMemsetAsync(heads, 0xFF, (size_t)TBL * sizeof(int), stream);

    const int eb = (E + 255) / 256;
    wpack_kernel<<<1, 64, 0, stream>>>(W, wsW);
    hist_kernel<<<eb, 256, 0, stream>>>(edst, cnt, E);
    scan_kernel<<<1, 1024, 0, stream>>>(cnt, off, NN, E);
    scatter_kernel<<<eb, 256, 0, stream>>>(edst, cnt, csr, E);
    build_hash_kernel<<<eb, 256, 0, stream>>>(esrc, edst, heads, nxt, E, (unsigned)NN);
    agg_csr_kernel<<<(NN + 3) / 4, 256, 0, stream>>>(feat, csr, off, agg, NN);
    fused_kernel<<<(E + 63) / 64, 256, 0, stream>>>(
        feat, esrc, edst, agg, heads, nxt, wsW, bias, out, E, (unsigned)NN);
}